// Round 2
// baseline (1429.685 us; speedup 1.0000x reference)
//
#include <hip/hip_runtime.h>

#define NN 8192
#define DD 128
#define EMB 64
#define INDIM 896
#define KD 8192

using half8   = __attribute__((ext_vector_type(8))) _Float16;
using floatx4 = __attribute__((ext_vector_type(4))) float;

__device__ __forceinline__ floatx4 ntld(const float* p) {
    return __builtin_nontemporal_load((const floatx4*)p);
}

// ---------------------------------------------------------------------------
// Algebra (cnt[c] = #{i : n_id[i]==c}):
//   S = L@x (2 K-split partials) ; xdiff = x - tau*(S0+S1)
//   xzT[d][c]   = cnt[c]*xdiff[c,d]              (fp16 [128][8192])
//   Y1 = K@xz  (M=16384,N=128)
//   z2T[k1*128+d][c] = cnt[c]*Y1[k1][c][d]       (fp16 [256][8192])
//   Y2 = K@z2  (M=16384,N=256)
//   E[r] = tanh(feat(r).W + b), out[j] = E[n_id[j]]
// ---------------------------------------------------------------------------

__global__ void hist_k(const int* __restrict__ n_id, float* __restrict__ cnt) {
    int i = blockIdx.x * blockDim.x + threadIdx.x;
    if (i < NN) atomicAdd(&cnt[n_id[i]], 1.0f);
}

// dst fp16 [Cd][R] = (cnt ? cnt[r] : 1) * src fp32 [R][Cd], transposed
__global__ __launch_bounds__(256)
void transpose_cvt(const float* __restrict__ src, const float* __restrict__ cnt,
                   _Float16* __restrict__ dst, int R, int Cd) {
    __shared__ float tile[64][65];
    const int r0 = blockIdx.y * 64, c0 = blockIdx.x * 64;
    const int t = threadIdx.x;
    const int c4 = (t & 15) * 4;
    const int rb = t >> 4;
#pragma unroll
    for (int i = 0; i < 4; ++i) {
        int r = rb + i * 16;
        float4 v = *(const float4*)&src[(size_t)(r0 + r) * Cd + c0 + c4];
        float s = cnt ? cnt[r0 + r] : 1.0f;
        tile[r][c4 + 0] = v.x * s;
        tile[r][c4 + 1] = v.y * s;
        tile[r][c4 + 2] = v.z * s;
        tile[r][c4 + 3] = v.w * s;
    }
    __syncthreads();
#pragma unroll
    for (int p = 0; p < 2; ++p) {
        int f = t + p * 256;
        int cc = f >> 3, rseg = f & 7;
        half8 h;
#pragma unroll
        for (int j = 0; j < 8; ++j) h[j] = (_Float16)tile[rseg * 8 + j][cc];
        *(half8*)&dst[(size_t)(c0 + cc) * R + r0 + rseg * 8] = h;
    }
}

__global__ void fuse_xdiff(const float* __restrict__ x, const float* __restrict__ S0,
                           const float* __restrict__ S1, const float* __restrict__ tau,
                           float* __restrict__ xdiff) {
    int i = blockIdx.x * blockDim.x + threadIdx.x;   // over N*128
    xdiff[i] = x[i] - tau[0] * (S0[i] + S1[i]);
}

// ---------------------------------------------------------------------------
// Streaming GEMM: C[M][NT*16] = A[M][KD](fp32) @ BT[NT*16][KD](fp16)^T
// One wave per block; each wave owns 32 rows (2 m-tiles) x all NT n-tiles.
// No LDS, no barriers. A: depth-2 register prefetch (issued 2 K-steps = ~1.5k cy
// ahead of use), non-temporal so the stream doesn't evict B from L2.
// B: just-in-time from L2 (xzT/z2T are 2-4 MB, L2-resident); its latency hides
// under the A vmcnt wait. fp32->fp16 cvt in registers.
// ---------------------------------------------------------------------------
template<int NT, bool PRE>
__device__ __forceinline__ void gstep(const float* __restrict__ Ap,
                                      const _Float16* __restrict__ Bp, int ko,
                                      floatx4 (&ab)[2][2][2], int slot,
                                      floatx4 (&acc)[2][NT]) {
    // issue B loads first: their L2 latency overlaps the A vmcnt wait below
    half8 bb[NT];
#pragma unroll
    for (int nt = 0; nt < NT; ++nt)
        bb[nt] = *(const half8*)(Bp + (size_t)nt * 16 * KD + ko);

    // cvt A (compiler inserts counted vmcnt wait for ab[slot] here)
    half8 ha[2];
#pragma unroll
    for (int mt = 0; mt < 2; ++mt) {
        const floatx4 u = ab[slot][mt][0];
        const floatx4 v = ab[slot][mt][1];
        half8 h;
        h[0] = (_Float16)u[0]; h[1] = (_Float16)u[1]; h[2] = (_Float16)u[2]; h[3] = (_Float16)u[3];
        h[4] = (_Float16)v[0]; h[5] = (_Float16)v[1]; h[6] = (_Float16)v[2]; h[7] = (_Float16)v[3];
        ha[mt] = h;
    }

    // refill this slot for K-step ko+64 (consumed one full loop iteration later)
    if (PRE) {
        ab[slot][0][0] = ntld(Ap + ko + 64);
        ab[slot][0][1] = ntld(Ap + ko + 68);
        ab[slot][1][0] = ntld(Ap + 16L * KD + ko + 64);
        ab[slot][1][1] = ntld(Ap + 16L * KD + ko + 68);
    }

#pragma unroll
    for (int mt = 0; mt < 2; ++mt)
#pragma unroll
        for (int nt = 0; nt < NT; ++nt)
            acc[mt][nt] = __builtin_amdgcn_mfma_f32_16x16x32_f16(ha[mt], bb[nt], acc[mt][nt], 0, 0, 0);
}

template<int NT>
__global__ __launch_bounds__(64, 1)
void stream_gemm(const float* __restrict__ A, const _Float16* __restrict__ BT,
                 float* __restrict__ C, int kcnt, long cstride) {
    const int lane = threadIdx.x;
    const int l15 = lane & 15, q = lane >> 4;
    const long row0 = (long)blockIdx.x * 32;
    const int  kbeg = blockIdx.y * kcnt;          // K-split slab
    float* Cw = C + (long)blockIdx.y * cstride;   // partial-output buffer

    // MFMA fragment-direct addressing: lane l -> row l&15, k-seg (l>>4)*8
    const float*    Ap = A  + (row0 + l15) * (long)KD + kbeg + q * 8;
    const _Float16* Bp = BT + (long)l15 * KD + kbeg + q * 8;

    floatx4 acc[2][NT] = {};
    floatx4 ab[2][2][2];   // [slot][m-tile][half]

    // prologue: prefetch K-steps 0 and 32
#pragma unroll
    for (int s = 0; s < 2; ++s) {
        ab[s][0][0] = ntld(Ap + s * 32);
        ab[s][0][1] = ntld(Ap + s * 32 + 4);
        ab[s][1][0] = ntld(Ap + 16L * KD + s * 32);
        ab[s][1][1] = ntld(Ap + 16L * KD + s * 32 + 4);
    }

    int ko = 0;
#pragma unroll 1
    for (; ko < kcnt - 64; ko += 64) {
        gstep<NT, true>(Ap, Bp, ko,      ab, 0, acc);
        gstep<NT, true>(Ap, Bp, ko + 32, ab, 1, acc);
    }
    gstep<NT, false>(Ap, Bp, ko,      ab, 0, acc);
    gstep<NT, false>(Ap, Bp, ko + 32, ab, 1, acc);

    const int ldc = NT * 16;
#pragma unroll
    for (int mt = 0; mt < 2; ++mt)
#pragma unroll
        for (int nt = 0; nt < NT; ++nt)
#pragma unroll
            for (int r = 0; r < 4; ++r)
                Cw[(row0 + mt * 16 + q * 4 + r) * (long)ldc + nt * 16 + l15] = acc[mt][nt][r];
}

// ---------------------------------------------------------------------------
// Encoder: block = 256 threads = 4 waves, 32 rows (8 rows/thread).
// W staged through LDS in 128-row chunks -> W re-read drops 1.9 GB -> 59 MB.
// feat chunks map 1:1 onto source slabs (each 128-feature chunk = one slab).
// ---------------------------------------------------------------------------
__global__ __launch_bounds__(256)
void encoder_k(const float* __restrict__ xdiff, const float* __restrict__ Y1,
               const float* __restrict__ Y2, const float* __restrict__ W,
               const float* __restrict__ bvec, float* __restrict__ E) {
    __shared__ float feat[32][129];   // +1 pad: conflict-free staging writes
    __shared__ float Ws[128][65];
    const int t = threadIdx.x;
    const int e = t & 63;
    const int wv = t >> 6;            // wave id 0..3 -> rows wv*8..wv*8+7
    const size_t r0 = (size_t)blockIdx.x * 32;

    float acc[8];
#pragma unroll
    for (int r = 0; r < 8; ++r) acc[r] = 0.f;

    const float* srcs[7] = {
        xdiff + r0 * DD,
        Y1 + r0 * DD,
        Y1 + (NN + r0) * DD,
        Y2 + r0 * 256,
        Y2 + r0 * 256 + 128,
        Y2 + (NN + r0) * 256,
        Y2 + (NN + r0) * 256 + 128
    };
    const int ldv[7] = {128, 128, 128, 256, 256, 256, 256};

    const int fr = t >> 3;            // feat row 0..31
    const int fc = (t & 7) * 16;      // feat col base
    const int wr = t >> 1;            // W row 0..127
    const int wc = (t & 1) * 32;      // W col base

    for (int c = 0; c < 7; ++c) {
        __syncthreads();              // previous chunk's readers done
        const float* s = srcs[c] + (size_t)fr * ldv[c] + fc;
#pragma unroll
        for (int i = 0; i < 4; ++i) {
            float4 v = *(const float4*)(s + i * 4);
            feat[fr][fc + i * 4 + 0] = v.x;
            feat[fr][fc + i * 4 + 1] = v.y;
            feat[fr][fc + i * 4 + 2] = v.z;
            feat[fr][fc + i * 4 + 3] = v.w;
        }
        const float* wsrc = W + (size_t)(c * 128 + wr) * EMB + wc;
#pragma unroll
        for (int i = 0; i < 8; ++i) {
            float4 v = *(const float4*)(wsrc + i * 4);
            Ws[wr][wc + i * 4 + 0] = v.x;
            Ws[wr][wc + i * 4 + 1] = v.y;
            Ws[wr][wc + i * 4 + 2] = v.z;
            Ws[wr][wc + i * 4 + 3] = v.w;
        }
        __syncthreads();
        for (int j = 0; j < 128; ++j) {
            float w = Ws[j][e];
#pragma unroll
            for (int r = 0; r < 8; ++r)
                acc[r] += feat[wv * 8 + r][j] * w;   // feat read = LDS broadcast
        }
    }

    const float bb = bvec[e];
#pragma unroll
    for (int r = 0; r < 8; ++r)
        E[(r0 + wv * 8 + r) * EMB + e] = tanhf(acc[r] + bb);
}

__global__ void gather_k(const float* __restrict__ E,
                         const int* __restrict__ n_id,
                         float* __restrict__ out) {
    int i = blockIdx.x * blockDim.x + threadIdx.x;
    int j = i >> 6;
    int e = i & 63;
    out[i] = E[(size_t)n_id[j] * EMB + e];
}

extern "C" void kernel_launch(void* const* d_in, const int* in_sizes, int n_in,
                              void* d_out, int out_size, void* d_ws, size_t ws_size,
                              hipStream_t stream) {
    const float* x    = (const float*)d_in[0];
    const float* K    = (const float*)d_in[1];   // [2,8192,8192] -> [16384,8192]
    const float* L    = (const float*)d_in[2];
    const float* tau  = (const float*)d_in[3];
    const float* W    = (const float*)d_in[4];
    const float* b    = (const float*)d_in[5];
    const int*   n_id = (const int*)d_in[6];
    float* out = (float*)d_out;

    // workspace carve-up (floats / halfs) — same footprint as previous version
    float* ws = (float*)d_ws;
    float* cnt   = ws;                       // 8192 f
    float* S     = cnt + NN;                 // 1M f   (K-split partial 0)
    float* xdiff = S + NN * DD;              // 1M f
    float* Y1    = xdiff + NN * DD;          // 2M f
    float* Y2    = Y1 + 2 * NN * DD;         // 4M f
    float* E     = Y2 + 2 * NN * 256;        // 512K f
    _Float16* BT1 = (_Float16*)(E + NN * EMB);   // 1M h  (x^T)
    _Float16* xzT = BT1 + NN * DD;               // 1M h
    _Float16* z2T = xzT + NN * DD;               // 2M h
    float* S1 = (float*)z2T;                 // alias: S partial 1 (dead before z2T written)
    const long sstride = (long)(S1 - S);

    hipMemsetAsync(cnt, 0, NN * sizeof(float), stream);
    hist_k<<<32, 256, 0, stream>>>(n_id, cnt);

    // BT1 = x^T (fp16)
    transpose_cvt<<<dim3(2, 128), 256, 0, stream>>>(x, nullptr, BT1, NN, DD);

    // S = L @ x   (M=8192, N=128, 2-way K-split into S / S1 partials, no atomics)
    stream_gemm<8><<<dim3(256, 2), 64, 0, stream>>>(L, BT1, S, KD / 2, sstride);

    fuse_xdiff<<<NN * DD / 256, 256, 0, stream>>>(x, S, S1, tau, xdiff);

    // xzT = (cnt * xdiff)^T fp16
    transpose_cvt<<<dim3(2, 128), 256, 0, stream>>>(xdiff, cnt, xzT, NN, DD);

    // Y1 = K @ xz  (M=16384, N=128, single pass, no split)
    stream_gemm<8><<<dim3(512, 1), 64, 0, stream>>>(K, xzT, Y1, KD, 0);

    // z2T[k1*128+d][c] = cnt[c]*Y1[k1][c][d]
    transpose_cvt<<<dim3(2, 128), 256, 0, stream>>>(Y1, cnt, z2T, NN, DD);
    transpose_cvt<<<dim3(2, 128), 256, 0, stream>>>(Y1 + (size_t)NN * DD, cnt,
                                                    z2T + (size_t)DD * NN, NN, DD);

    // Y2 = K @ z2  (M=16384, N=256 in ONE pass — K read once, was twice)
    stream_gemm<16><<<dim3(512, 1), 64, 0, stream>>>(K, z2T, Y2, KD, 0);

    encoder_k<<<NN / 32, 256, 0, stream>>>(xdiff, Y1, Y2, W, b, E);
    gather_k<<<NN * EMB / 256, 256, 0, stream>>>(E, n_id, out);
}